// Round 8
// baseline (647.241 us; speedup 1.0000x reference)
//
#include <hip/hip_runtime.h>
#include <hip/hip_bf16.h>
#include <hip/hip_cooperative_groups.h>

// GraphSAGE 2-layer forward. N=100000, E=1250000, 64 -> 64 -> 32, fp32.
//
// Round-21: round-20's self-fusion reverted (it serialized 18us of work into
// the latency-bound agg64 kernel; occ 58->34). Back to round-18 bodies
// (best known 203.6us). New: the BUILD side (prep -> dense1||p1 -> p2) is
// fused into one cooperative kernel with grid.sync -- these phases are
// register-light (<=60 VGPR, enforced via __launch_bounds__(256,8) -> cap 64)
// and not gather-latency-bound, so the round-19 failure modes (VGPR 128,
// grid-stride serialization of latency-bound tiles) don't apply. p2 drops
// its 32KB LDS stage (bucket re-read, L2-hot; proven correct round-19) to
// keep LDS at 4.4KB / 8 blocks per CU. agg64_d2 / agg32 unchanged round-18.
//   build (coop): ph0 gcursor=0 + pack w1p/w2p; ph1 dense1 || p1; ph2 p2
//   agg64_d2    : h1 = relu(xs + mean t1n[src]); d_out=h1@Ws2+b2, t2n=bf16
//   agg32       : d_out += mean t2n[src]  (in place)
// Fallback: round-18 multi-dispatch sequence if coop unavailable.

namespace cg = cooperative_groups;

#define NF 64
#define BW 256            // bucket width (nodes); rel = dst & 255
#define BSH 8
#define MAXB 512          // max buckets (LDS arrays)
#define CAPMAX 8192       // max edges per bucket region (mean 3197)
#define P1_CHUNK 2048
#define H1S 68            // h1s row stride in floats

typedef __attribute__((ext_vector_type(8))) short short8;
typedef __attribute__((ext_vector_type(8))) unsigned short ushort8v;
typedef __attribute__((ext_vector_type(4))) float floatx4;

__device__ __forceinline__ short bf16hi(float v) {
    __hip_bfloat16 h = __float2bfloat16(v);
    return *(short*)&h;
}
__device__ __forceinline__ float bf2f(short s) {
    __hip_bfloat16 h = *(__hip_bfloat16*)&s;
    return __bfloat162float(h);
}
__device__ __forceinline__ float bits2f(unsigned short u) {
    unsigned int x = ((unsigned int)u) << 16;
    union { unsigned int i; float f; } c; c.i = x; return c.f;
}

// ================= phase bodies =================

// w1p: [n*64+k] hi, [+8192] lo; n = dense1 out col (0-63 self, 64-127 neigh).
// w2p: [n*64+k] hi, [+4096] lo; n = dense2 out col (0-31 self, 32-63 neigh).
__device__ __forceinline__ void prep_body(int v, int* __restrict__ gcursor,
        const float* __restrict__ Ws1, const float* __restrict__ Wn1,
        const float* __restrict__ Ws2, const float* __restrict__ Wn2,
        unsigned short* __restrict__ w1p, unsigned short* __restrict__ w2p) {
    const int tid = threadIdx.x;
    if (v == 0) {
        for (int i = tid; i < MAXB; i += 256) gcursor[i] = 0;
        return;
    }
    const int part = v - 1;                          // 0..3
    for (int i = tid; i < 32 * 64; i += 256) {       // w1: 32 cols per part
        int n = part * 32 + (i >> 6), k = i & 63;
        float w = (n < 64) ? Ws1[k * 64 + n] : Wn1[k * 64 + (n - 64)];
        short hv = bf16hi(w);
        w1p[n * 64 + k] = (unsigned short)hv;
        w1p[8192 + n * 64 + k] = (unsigned short)bf16hi(w - bf2f(hv));
    }
    for (int i = tid; i < 16 * 64; i += 256) {       // w2: 16 cols per part
        int n = part * 16 + (i >> 6), k = i & 63;
        float w = (n < 32) ? Ws2[k * 32 + n] : Wn2[k * 32 + (n - 32)];
        short hv = bf16hi(w);
        w2p[n * 64 + k] = (unsigned short)hv;
        w2p[4096 + n * 64 + k] = (unsigned short)bf16hi(w - bf2f(hv));
    }
}

__device__ __forceinline__ void p1_body(int bid, int* __restrict__ pool,
        const int* __restrict__ src, const int* __restrict__ dst,
        int* __restrict__ gcursor, unsigned* __restrict__ bucket,
        int E, int nbuckets) {
    int* cnt   = pool;                               // [MAXB]
    int* cbase = pool + MAXB;                        // [MAXB]
    const int tid = threadIdx.x;
    const int beg = bid * P1_CHUNK;
    const int end = min(E, beg + P1_CHUNK);
    for (int i = tid; i < nbuckets; i += 256) cnt[i] = 0;
    __syncthreads();
    for (int e = beg + tid; e < end; e += 256)
        atomicAdd(&cnt[dst[e] >> BSH], 1);
    __syncthreads();
    for (int i = tid; i < nbuckets; i += 256) {
        int c = cnt[i];
        cbase[i] = c ? atomicAdd(&gcursor[i], c) : 0;
        cnt[i] = 0;                                  // reuse as local cursor
    }
    __syncthreads();
    for (int e = beg + tid; e < end; e += 256) {
        int d = dst[e];
        int r = d >> BSH;
        int p = cbase[r] + atomicAdd(&cnt[r], 1);
        if (p < CAPMAX)                              // clamp: no OOB even if skewed
            bucket[(size_t)r * CAPMAX + p] = ((unsigned)src[e] << BSH) | (unsigned)(d & (BW - 1));
    }
    __syncthreads();                                 // pool reuse guard
}

__device__ __forceinline__ void dense1_body(int vb,
        const float* __restrict__ X, const unsigned short* __restrict__ w1p,
        const float* __restrict__ bias,
        float* __restrict__ outA, unsigned short* __restrict__ outB, int N) {
    constexpr int NT = 8, NSELF = 4;
    const int tid = threadIdx.x;
    const int lane = tid & 63;
    const int wid  = tid >> 6;
    const int m = lane & 15, quad = lane >> 4;
    const int rowblk = vb * 128 + wid * 32;

    floatx4 acc[2][NT];
    #pragma unroll
    for (int rt = 0; rt < 2; ++rt)
        #pragma unroll
        for (int t = 0; t < NT; ++t) acc[rt][t] = (floatx4)(0.f);

    short8 ah[2][2], al[2][2];   // [rowset][k-half]
    #pragma unroll
    for (int rt = 0; rt < 2; ++rt) {
        int r = rowblk + rt * 16 + m;
        if (r >= N) r = N - 1;                       // clamped load, store guarded
        const float* xp = X + (size_t)r * 64 + quad * 8;
        #pragma unroll
        for (int h = 0; h < 2; ++h) {
            floatx4 f0 = *(const floatx4*)(xp + h * 32);
            floatx4 f1 = *(const floatx4*)(xp + h * 32 + 4);
            short8 hi, lo;
            #pragma unroll
            for (int j = 0; j < 4; ++j) {
                short hv = bf16hi(f0[j]);
                hi[j] = hv; lo[j] = bf16hi(f0[j] - bf2f(hv));
                short hv2 = bf16hi(f1[j]);
                hi[4 + j] = hv2; lo[4 + j] = bf16hi(f1[j] - bf2f(hv2));
            }
            ah[rt][h] = hi; al[rt][h] = lo;
        }
    }

    #pragma unroll
    for (int t = 0; t < NT; ++t) {
        int n = t * 16 + m;
        const unsigned short* ph = w1p + n * 64 + quad * 8;
        const unsigned short* pl = ph + 8192;
        #pragma unroll
        for (int h = 0; h < 2; ++h) {
            short8 bh = *(const short8*)(ph + h * 32);
            short8 bl = *(const short8*)(pl + h * 32);
            #pragma unroll
            for (int rt = 0; rt < 2; ++rt) {
                acc[rt][t] = __builtin_amdgcn_mfma_f32_16x16x32_bf16(ah[rt][h], bh, acc[rt][t], 0, 0, 0);
                acc[rt][t] = __builtin_amdgcn_mfma_f32_16x16x32_bf16(al[rt][h], bh, acc[rt][t], 0, 0, 0);
                acc[rt][t] = __builtin_amdgcn_mfma_f32_16x16x32_bf16(ah[rt][h], bl, acc[rt][t], 0, 0, 0);
            }
        }
    }

    #pragma unroll
    for (int rt = 0; rt < 2; ++rt) {
        #pragma unroll
        for (int t = 0; t < NT; ++t) {
            #pragma unroll
            for (int r4 = 0; r4 < 4; ++r4) {
                int row = rowblk + rt * 16 + quad * 4 + r4;
                if (row < N) {
                    if (t < NSELF) {
                        int col = t * 16 + m;
                        outA[(size_t)row * 64 + col] = acc[rt][t][r4] + bias[col];
                    } else {
                        int col = (t - NSELF) * 16 + m;
                        outB[(size_t)row * 64 + col] = (unsigned short)bf16hi(acc[rt][t][r4]);
                    }
                }
            }
        }
    }
}

// p2 without LDS staging (bucket re-read from L2) -- 2 KB pool only.
__device__ __forceinline__ void p2_nostage_body(int r, int* __restrict__ pool,
        const unsigned* __restrict__ bucket, const int* __restrict__ gcursor,
        int* __restrict__ row_start, int* __restrict__ csr_src,
        int N, int nbuckets) {
    int* cnt  = pool;                                // [BW]
    int* excl = pool + BW;                           // [BW]
    const int tid = threadIdx.x;

    // base = sum_{i<r} min(gcursor[i], CAPMAX)
    int partial = 0;
    for (int i = tid; i < r; i += 256) partial += min(gcursor[i], CAPMAX);
    excl[tid] = partial;
    __syncthreads();
    for (int off = 128; off > 0; off >>= 1) {
        if (tid < off) excl[tid] += excl[tid + off];
        __syncthreads();
    }
    const int base = excl[0];
    const int sz = min(gcursor[r], CAPMAX);
    const unsigned* bsrc = bucket + (size_t)r * CAPMAX;
    __syncthreads();

    cnt[tid] = 0;
    __syncthreads();
    for (int i = tid; i < sz; i += 256)
        atomicAdd(&cnt[bsrc[i] & (BW - 1)], 1);
    __syncthreads();
    excl[tid] = cnt[tid];
    __syncthreads();
    for (int off = 1; off < BW; off <<= 1) {         // inclusive Hillis-Steele
        int v0 = (tid >= off) ? excl[tid - off] : 0;
        __syncthreads();
        excl[tid] += v0;
        __syncthreads();
    }
    int node = r * BW + tid;
    if (node < N) row_start[node] = base + excl[tid] - cnt[tid];
    if (r == nbuckets - 1 && tid == 0) row_start[N] = base + sz;
    __syncthreads();
    cnt[tid] = excl[tid] - cnt[tid];                 // exclusive cursors
    __syncthreads();
    for (int i = tid; i < sz; i += 256) {            // re-read bucket (L2-hot)
        unsigned v = bsrc[i];
        int p = atomicAdd(&cnt[v & (BW - 1)], 1);
        csr_src[base + p] = (int)(v >> BSH);
    }
    __syncthreads();                                 // pool reuse guard
}

// ================= cooperative build kernel =================
// VGPR hard-capped at 64 via min-waves/EU=8 (round-19's 128-VGPR failure fix).

__global__ __launch_bounds__(256, 8) void build_kernel(
        const int* __restrict__ src, const int* __restrict__ dst,
        int* __restrict__ gcursor, unsigned* __restrict__ bucket,
        const float* __restrict__ X,
        const float* __restrict__ Ws1, const float* __restrict__ Wn1,
        const float* __restrict__ b1,
        const float* __restrict__ Ws2, const float* __restrict__ Wn2,
        unsigned short* __restrict__ w1p, unsigned short* __restrict__ w2p,
        float* __restrict__ bufA, unsigned short* __restrict__ t1n,
        int* __restrict__ row_start, int* __restrict__ csr_src,
        int N, int E, int nbuckets, int dblocks, int p1blocks) {
    __shared__ __align__(16) int pool[2 * MAXB];     // 4 KB
    cg::grid_group grid = cg::this_grid();
    const int gb = gridDim.x;
    const int bid = blockIdx.x;

    // ---- phase0: gcursor zero + weight pack ----
    for (int v = bid; v < 5; v += gb)
        prep_body(v, gcursor, Ws1, Wn1, Ws2, Wn2, w1p, w2p);
    __threadfence();
    grid.sync();

    // ---- phase1: dense1 || p1 (one virtual block each at full grid) ----
    const int ph1 = dblocks + p1blocks;
    for (int v = bid; v < ph1; v += gb) {
        if (v < dblocks) dense1_body(v, X, w1p, b1, bufA, t1n, N);
        else p1_body(v - dblocks, pool, src, dst, gcursor, bucket, E, nbuckets);
    }
    __threadfence();
    grid.sync();

    // ---- phase2: p2 CSR (no stage) ----
    for (int v = bid; v < nbuckets; v += gb)
        p2_nostage_body(v, pool, bucket, gcursor, row_start, csr_src, N, nbuckets);
}

// ================= standalone kernels (round-18 proven path) =================

__global__ __launch_bounds__(256) void prep_kernel(
        int* __restrict__ gcursor,
        const float* __restrict__ Ws1, const float* __restrict__ Wn1,
        const float* __restrict__ Ws2, const float* __restrict__ Wn2,
        unsigned short* __restrict__ w1p, unsigned short* __restrict__ w2p) {
    prep_body(blockIdx.x, gcursor, Ws1, Wn1, Ws2, Wn2, w1p, w2p);
}

__global__ __launch_bounds__(256) void p1_dense1_kernel(
        const int* __restrict__ src, const int* __restrict__ dst,
        int* __restrict__ gcursor, unsigned* __restrict__ bucket,
        int E, int nbuckets, int dblocks,
        const float* __restrict__ X,
        const unsigned short* __restrict__ w1p,
        const float* __restrict__ bias,
        float* __restrict__ outA, unsigned short* __restrict__ outB,
        int N) {
    __shared__ __align__(16) int pool[2 * MAXB];
    if ((int)blockIdx.x >= dblocks)
        p1_body(blockIdx.x - dblocks, pool, src, dst, gcursor, bucket, E, nbuckets);
    else
        dense1_body(blockIdx.x, X, w1p, bias, outA, outB, N);
}

// staged p2 for the fallback path (32 KB LDS, round-18 proven)
__global__ __launch_bounds__(256) void p2_csr_kernel(const unsigned* __restrict__ bucket,
                                                     const int* __restrict__ gcursor,
                                                     int* __restrict__ row_start,
                                                     int* __restrict__ csr_src,
                                                     int N, int nbuckets) {
    __shared__ unsigned stage[CAPMAX];   // 32 KB
    __shared__ int cnt[BW];
    __shared__ int excl[BW];
    const int r = blockIdx.x;
    const int tid = threadIdx.x;

    int partial = 0;
    for (int i = tid; i < r; i += 256) partial += min(gcursor[i], CAPMAX);
    excl[tid] = partial;
    __syncthreads();
    for (int off = 128; off > 0; off >>= 1) {
        if (tid < off) excl[tid] += excl[tid + off];
        __syncthreads();
    }
    const int base = excl[0];
    const int sz = min(gcursor[r], CAPMAX);
    const unsigned* bsrc = bucket + (size_t)r * CAPMAX;
    __syncthreads();

    cnt[tid] = 0;
    __syncthreads();
    for (int i = tid; i < sz; i += 256) {
        unsigned v = bsrc[i];
        stage[i] = v;
        atomicAdd(&cnt[v & (BW - 1)], 1);
    }
    __syncthreads();
    excl[tid] = cnt[tid];
    __syncthreads();
    for (int off = 1; off < BW; off <<= 1) {
        int v0 = (tid >= off) ? excl[tid - off] : 0;
        __syncthreads();
        excl[tid] += v0;
        __syncthreads();
    }
    int node = r * BW + tid;
    if (node < N) row_start[node] = base + excl[tid] - cnt[tid];
    if (r == nbuckets - 1 && tid == 0) row_start[N] = base + sz;
    __syncthreads();
    cnt[tid] = excl[tid] - cnt[tid];
    __syncthreads();
    for (int i = tid; i < sz; i += 256) {
        unsigned v = stage[i];
        int p = atomicAdd(&cnt[v & (BW - 1)], 1);
        csr_src[base + p] = (int)(v >> BSH);
    }
}

// ---------------- fused agg64 + dense2 (round-18, with index prefetch) ------

__global__ __launch_bounds__(256) void agg64_d2_kernel(
        const unsigned short* __restrict__ t1n,      // [N][64] bf16 bits
        const float* __restrict__ xs,                // [N][64] self+bias
        const int* __restrict__ row_start,
        const int* __restrict__ csr_src,
        const unsigned short* __restrict__ w2p,      // packed hi/lo fragments
        const float* __restrict__ b2,                // [32]
        float* __restrict__ outD,                    // [N][32] (d_out)
        unsigned short* __restrict__ t2n,            // [N][32] bf16 bits
        int N, int E) {
    __shared__ float h1s[16][H1S];                   // 4.25 KB, padded stride
    const int tid = threadIdx.x;
    const int lane = tid & 63;
    const int wid  = tid >> 6;
    const int half = lane >> 5;                      // node select within pair
    const int g = (lane >> 3) & 3;                   // 4 groups of 8 per node
    const int c = lane & 7;
    const int nbase = blockIdx.x * 16;

    const int ln0 = wid * 4 + half;                  // this half-wave's 2 nodes
    const int ln1 = ln0 + 2;
    const int n0 = nbase + ln0, n1 = nbase + ln1;
    int beg0 = 0, end0 = 0, beg1 = 0, end1 = 0;
    if (n0 < N) { beg0 = row_start[n0]; end0 = row_start[n0 + 1]; }
    if (n1 < N) { beg1 = row_start[n1]; end1 = row_start[n1 + 1]; }

    float a0[8] = {0.f, 0.f, 0.f, 0.f, 0.f, 0.f, 0.f, 0.f};
    float a1[8] = {0.f, 0.f, 0.f, 0.f, 0.f, 0.f, 0.f, 0.f};
    int j0 = beg0 + g, j1 = beg1 + g;
    const int Em1 = E - 1;
    // prefetched index set for the current iteration
    int i0 = csr_src[min(j0, Em1)];
    int i1 = csr_src[min(j0 + 4, Em1)];
    int i2 = csr_src[min(j1, Em1)];
    int i3 = csr_src[min(j1 + 4, Em1)];
    while ((j0 < end0) || (j1 < end1)) {
        int s0 = ((unsigned)i0 < (unsigned)N) ? i0 : 0;
        int s1 = ((unsigned)i1 < (unsigned)N) ? i1 : 0;
        int s2 = ((unsigned)i2 < (unsigned)N) ? i2 : 0;
        int s3 = ((unsigned)i3 < (unsigned)N) ? i3 : 0;
        // 4 concurrent row gathers
        ushort8v u0 = *(const ushort8v*)(t1n + (size_t)s0 * 64 + c * 8);
        ushort8v u1 = *(const ushort8v*)(t1n + (size_t)s1 * 64 + c * 8);
        ushort8v u2 = *(const ushort8v*)(t1n + (size_t)s2 * 64 + c * 8);
        ushort8v u3 = *(const ushort8v*)(t1n + (size_t)s3 * 64 + c * 8);
        // prefetch next iteration's indices (overlap gather latency)
        i0 = csr_src[min(j0 + 8, Em1)];
        i1 = csr_src[min(j0 + 12, Em1)];
        i2 = csr_src[min(j1 + 8, Em1)];
        i3 = csr_src[min(j1 + 12, Em1)];
        const bool c00 = j0 < end0, c01 = j0 + 4 < end0;
        const bool c10 = j1 < end1, c11 = j1 + 4 < end1;
        #pragma unroll
        for (int i = 0; i < 8; ++i) {
            a0[i] += (c00 ? bits2f(u0[i]) : 0.f) + (c01 ? bits2f(u1[i]) : 0.f);
            a1[i] += (c10 ? bits2f(u2[i]) : 0.f) + (c11 ? bits2f(u3[i]) : 0.f);
        }
        j0 += 8; j1 += 8;
    }

    // issue tail loads now; latency hides under reduce + h1s + barrier
    const int m = lane & 15, quad = lane >> 4;
    const int coln = wid * 16 + m;
    const unsigned short* pb = w2p + coln * 64 + quad * 8;
    short8 bhf0 = *(const short8*)(pb);
    short8 bhf1 = *(const short8*)(pb + 32);
    short8 blf0 = *(const short8*)(pb + 4096);
    short8 blf1 = *(const short8*)(pb + 4096 + 32);

    floatx4 x00 = (floatx4)(0.f), x01 = (floatx4)(0.f);
    floatx4 x10 = (floatx4)(0.f), x11 = (floatx4)(0.f);
    if (g == 0) {
        if (n0 < N) {
            const float* p = xs + (size_t)n0 * 64 + c * 8;
            x00 = *(const floatx4*)p; x01 = *(const floatx4*)(p + 4);
        }
        if (n1 < N) {
            const float* p = xs + (size_t)n1 * 64 + c * 8;
            x10 = *(const floatx4*)p; x11 = *(const floatx4*)(p + 4);
        }
    }

    #pragma unroll
    for (int i = 0; i < 8; ++i) {                    // reduce over 4 groups (in-half)
        float v = a0[i];
        v += __shfl_xor(v, 8);
        v += __shfl_xor(v, 16);
        a0[i] = v;
        float w = a1[i];
        w += __shfl_xor(w, 8);
        w += __shfl_xor(w, 16);
        a1[i] = w;
    }
    if (g == 0) {                                    // 8 lanes per half write rows
        floatx4 h0, h1v;
        if (n0 < N) {
            float invd = 1.0f / fmaxf((float)(end0 - beg0), 1.0f);
            #pragma unroll
            for (int i = 0; i < 4; ++i) {
                h0[i]  = fmaxf(x00[i] + a0[i] * invd, 0.f);
                h1v[i] = fmaxf(x01[i] + a0[4 + i] * invd, 0.f);
            }
        } else { h0 = (floatx4)(0.f); h1v = (floatx4)(0.f); }
        *(floatx4*)&h1s[ln0][c * 8]     = h0;
        *(floatx4*)&h1s[ln0][c * 8 + 4] = h1v;
        if (n1 < N) {
            float invd = 1.0f / fmaxf((float)(end1 - beg1), 1.0f);
            #pragma unroll
            for (int i = 0; i < 4; ++i) {
                h0[i]  = fmaxf(x10[i] + a1[i] * invd, 0.f);
                h1v[i] = fmaxf(x11[i] + a1[4 + i] * invd, 0.f);
            }
        } else { h0 = (floatx4)(0.f); h1v = (floatx4)(0.f); }
        *(floatx4*)&h1s[ln1][c * 8]     = h0;
        *(floatx4*)&h1s[ln1][c * 8 + 4] = h1v;
    }
    __syncthreads();                                 // h1 tile ready

    // dense2: wave wid -> output cols wid*16 .. wid*16+15
    short8 ah[2], al[2];                             // A = h1s, split hi/lo
    #pragma unroll
    for (int h = 0; h < 2; ++h) {
        const float* hp = &h1s[m][quad * 8 + h * 32];
        floatx4 f0 = *(const floatx4*)hp;
        floatx4 f1 = *(const floatx4*)(hp + 4);
        short8 hi, lo;
        #pragma unroll
        for (int j = 0; j < 4; ++j) {
            short hv = bf16hi(f0[j]);
            hi[j] = hv; lo[j] = bf16hi(f0[j] - bf2f(hv));
            short hv2 = bf16hi(f1[j]);
            hi[4 + j] = hv2; lo[4 + j] = bf16hi(f1[j] - bf2f(hv2));
        }
        ah[h] = hi; al[h] = lo;
    }
    floatx4 acc2 = (floatx4)(0.f);
    acc2 = __builtin_amdgcn_mfma_f32_16x16x32_bf16(ah[0], bhf0, acc2, 0, 0, 0);
    acc2 = __builtin_amdgcn_mfma_f32_16x16x32_bf16(al[0], bhf0, acc2, 0, 0, 0);
    acc2 = __builtin_amdgcn_mfma_f32_16x16x32_bf16(ah[0], blf0, acc2, 0, 0, 0);
    acc2 = __builtin_amdgcn_mfma_f32_16x16x32_bf16(ah[1], bhf1, acc2, 0, 0, 0);
    acc2 = __builtin_amdgcn_mfma_f32_16x16x32_bf16(al[1], bhf1, acc2, 0, 0, 0);
    acc2 = __builtin_amdgcn_mfma_f32_16x16x32_bf16(ah[1], blf1, acc2, 0, 0, 0);
    #pragma unroll
    for (int r4 = 0; r4 < 4; ++r4) {
        int node = nbase + quad * 4 + r4;
        if (node < N) {
            if (coln < 32) outD[(size_t)node * 32 + coln] = acc2[r4] + b2[coln];
            else t2n[(size_t)node * 32 + (coln - 32)] = (unsigned short)bf16hi(acc2[r4]);
        }
    }
}

// ---------------- agg32 (round-18): 16-lane group per node ----------------

__global__ __launch_bounds__(256) void agg32_kernel(float* io,  // [N][32] (d_out)
                                                    const unsigned short* __restrict__ t2n,
                                                    const int* __restrict__ row_start,
                                                    const int* __restrict__ csr_src,
                                                    int N, int E) {
    const int tid = threadIdx.x;
    const int lane = tid & 63;
    const int wid = tid >> 6;
    const int slot = lane >> 4;                      // 4 nodes per wave
    const int g = (lane >> 2) & 3;                   // 4 edge-groups per node
    const int c = lane & 3;                          // 16B chunk of 64B row
    const int n = blockIdx.x * 16 + wid * 4 + slot;

    int beg = 0, end = 0;
    if (n < N) { beg = row_start[n]; end = row_start[n + 1]; }

    // hoist in-place read: overlaps the gather chain instead of trailing it
    floatx4 s0v = (floatx4)(0.f), s1v = (floatx4)(0.f);
    size_t o = (size_t)n * 32 + c * 8;
    if (n < N && g == 0) {
        s0v = *(const floatx4*)(io + o);
        s1v = *(const floatx4*)(io + o + 4);
    }

    float acc[8] = {0.f, 0.f, 0.f, 0.f, 0.f, 0.f, 0.f, 0.f};
    const int Em1 = E - 1;
    for (int j = beg + g; j < end; j += 8) {
        int j2 = j + 4;
        int s0 = csr_src[j];                         // j < end <= E guaranteed
        int s1 = csr_src[min(j2, Em1)];
        s0 = ((unsigned)s0 < (unsigned)N) ? s0 : 0;
        s1 = ((unsigned)s1 < (unsigned)N) ? s1 : 0;
        ushort8v u0 = *(const ushort8v*)(t2n + (size_t)s0 * 32 + c * 8);
        ushort8v u1 = *(const ushort8v*)(t2n + (size_t)s1 * 32 + c * 8);
        const bool c1 = j2 < end;
        #pragma unroll
        for (int i = 0; i < 8; ++i)
            acc[i] += bits2f(u0[i]) + (c1 ? bits2f(u1[i]) : 0.f);
    }
    #pragma unroll
    for (int i = 0; i < 8; ++i) {                    // reduce over 4 groups (16-lane)
        float v = acc[i];
        v += __shfl_xor(v, 4);
        v += __shfl_xor(v, 8);
        acc[i] = v;
    }
    if (n < N && g == 0) {
        float inv = 1.0f / fmaxf((float)(end - beg), 1.0f);
        floatx4 r0, r1;
        #pragma unroll
        for (int i = 0; i < 4; ++i) {
            r0[i] = s0v[i] + acc[i] * inv;
            r1[i] = s1v[i] + acc[4 + i] * inv;
        }
        *(floatx4*)(io + o) = r0;
        *(floatx4*)(io + o + 4) = r1;
    }
}

// ---------------- fallback (round-2 atomic path) ----------------

__global__ __launch_bounds__(256) void deg_kernel(const int* __restrict__ dst,
                                                  float* __restrict__ deg, int E) {
    int e = blockIdx.x * blockDim.x + threadIdx.x;
    if (e < E) atomicAdd(&deg[dst[e]], 1.0f);
}

__global__ __launch_bounds__(256) void agg_atomic_kernel(const float* __restrict__ feats,
                                                         const int* __restrict__ src,
                                                         const int* __restrict__ dst,
                                                         float* __restrict__ agg, int E) {
    int tid = blockIdx.x * blockDim.x + threadIdx.x;
    if (tid >= E * NF) return;
    int e = tid >> 6, f = tid & 63;
    atomicAdd(&agg[(size_t)dst[e] * NF + f], feats[(size_t)src[e] * NF + f]);
}

__global__ __launch_bounds__(256) void layer1_fb_kernel(const float* __restrict__ x,
                                                        const float* __restrict__ agg,
                                                        const float* __restrict__ deg,
                                                        const float* __restrict__ Wself,
                                                        const float* __restrict__ Wneigh,
                                                        const float* __restrict__ b,
                                                        float* __restrict__ h1, int N) {
    int tid = blockIdx.x * blockDim.x + threadIdx.x;
    if (tid >= N * NF) return;
    int n = tid >> 6, c = tid & 63;
    float inv = 1.0f / fmaxf(deg[n], 1.0f);
    const float* xrow = x + (size_t)n * NF;
    const float* arow = agg + (size_t)n * NF;
    float acc = b[c];
    #pragma unroll
    for (int k = 0; k < NF; ++k) {
        acc += xrow[k] * Wself[k * NF + c];
        acc += (arow[k] * inv) * Wneigh[k * NF + c];
    }
    h1[tid] = fmaxf(acc, 0.f);
}

__global__ __launch_bounds__(256) void layer2_fb_kernel(const float* __restrict__ h1,
                                                        const float* __restrict__ agg,
                                                        const float* __restrict__ deg,
                                                        const float* __restrict__ Wself,
                                                        const float* __restrict__ Wneigh,
                                                        const float* __restrict__ b,
                                                        float* __restrict__ out, int N) {
    int tid = blockIdx.x * blockDim.x + threadIdx.x;
    if (tid >= N * 32) return;
    int n = tid >> 5, c = tid & 31;
    float inv = 1.0f / fmaxf(deg[n], 1.0f);
    const float* hrow = h1 + (size_t)n * NF;
    const float* arow = agg + (size_t)n * NF;
    float acc = b[c];
    #pragma unroll
    for (int k = 0; k < NF; ++k) {
        acc += hrow[k] * Wself[k * 32 + c];
        acc += (arow[k] * inv) * Wneigh[k * 32 + c];
    }
    out[tid] = acc;
}

// ---------------- launch ----------------

extern "C" void kernel_launch(void* const* d_in, const int* in_sizes, int n_in,
                              void* d_out, int out_size, void* d_ws, size_t ws_size,
                              hipStream_t stream) {
    const float* x        = (const float*)d_in[0];
    const int*   src      = (const int*)d_in[1];
    const int*   dst      = (const int*)d_in[2];
    const float* W_self1  = (const float*)d_in[3];
    const float* W_neigh1 = (const float*)d_in[4];
    const float* b1       = (const float*)d_in[5];
    const float* W_self2  = (const float*)d_in[6];
    const float* W_neigh2 = (const float*)d_in[7];
    const float* b2       = (const float*)d_in[8];
    float* out = (float*)d_out;

    const int N = in_sizes[0] / NF;          // 100000
    const int E = in_sizes[1];               // 1250000
    const int nbuckets = (N + BW - 1) / BW;  // 391

    // ws layout; gather tables 128B-aligned (round-10 proven)
    const size_t rsPad = ((size_t)N + 8) & ~7ull;
    int* gcursor   = (int*)d_ws;                      // [MAXB]
    unsigned short* w2p = (unsigned short*)(gcursor + MAXB);  // [8192] (16 KB)
    unsigned short* w1p = w2p + 8192;                 // [16384] (32 KB)
    int* row_start = (int*)(w1p + 16384);             // [N+1] padded
    int* csr_src   = row_start + rsPad;               // [E]
    uintptr_t pa = (uintptr_t)(csr_src + (((size_t)E + 7) & ~7ull));
    pa = (pa + 127) & ~(uintptr_t)127;                // 128B align
    float* bufA = (float*)pa;                         // [N][64] f32 (xs)
    unsigned* bucket = (unsigned*)bufA;               // alias (serialized fallback only)
    unsigned short* t1n = (unsigned short*)(bufA + (size_t)N * NF);  // [N][64] bf16
    unsigned short* t2n = t1n + (size_t)N * NF;                      // [N][32] bf16
    size_t need = (size_t)((char*)(t2n + (size_t)N * 32) - (char*)d_ws);  // ~50.3 MB

    bool fast = ws_size >= need
             && E > 0 && N > 0
             && nbuckets <= MAXB
             && (size_t)nbuckets * CAPMAX <= (size_t)N * NF
             && (size_t)E * 2 / (size_t)nbuckets <= CAPMAX
             && N < (1 << 24)
             && out_size >= N * 32;

    if (fast) {
        int dblocks  = (N + 127) / 128;
        int p1blocks = (E + P1_CHUNK - 1) / P1_CHUNK;
        unsigned* bucket2 = (unsigned*)(t2n + (((size_t)N * 32 + 63) & ~63ull));
        size_t need2 = (size_t)((char*)(bucket2 + (size_t)nbuckets * CAPMAX) - (char*)d_ws);
        const bool disjoint = ws_size >= need2;

        // cooperative capability + residency cap (cached)
        static int s_cap = -2;
        if (s_cap == -2) {
            int dev = 0; hipGetDevice(&dev);
            int coop = 0;
            hipDeviceGetAttribute(&coop, hipDeviceAttributeCooperativeLaunch, dev);
            if (coop) {
                int cus = 0, bpc = 0;
                hipDeviceGetAttribute(&cus, hipDeviceAttributeMultiprocessorCount, dev);
                hipOccupancyMaxActiveBlocksPerMultiprocessor(&bpc, build_kernel, 256, 0);
                s_cap = (cus > 0 && bpc > 0) ? cus * bpc : -1;
            } else s_cap = -1;
        }

        bool built = false;
        if (disjoint && s_cap >= 256) {
            int grid = dblocks + p1blocks;           // 1393
            if (grid > s_cap) grid = s_cap;          // grid-stride handles rest
            const int* src_a = src; const int* dst_a = dst;
            int* gcur_a = gcursor; unsigned* buck_a = bucket2;
            const float* x_a = x;
            const float* ws1_a = W_self1; const float* wn1_a = W_neigh1;
            const float* b1_a = b1;
            const float* ws2_a = W_self2; const float* wn2_a = W_neigh2;
            unsigned short* w1p_a = w1p; unsigned short* w2p_a = w2p;
            float* bufA_a = bufA; unsigned short* t1n_a = t1n;
            int* rs_a = row_start; int* csr_a = csr_src;
            int N_a = N, E_a = E, nb_a = nbuckets, db_a = dblocks, pb_a = p1blocks;
            void* kargs[] = {
                (void*)&src_a, (void*)&dst_a, (void*)&gcur_a, (void*)&buck_a,
                (void*)&x_a, (void*)&ws1_a, (void*)&wn1_a, (void*)&b1_a,
                (void*)&ws2_a, (void*)&wn2_a,
                (void*)&w1p_a, (void*)&w2p_a, (void*)&bufA_a, (void*)&t1n_a,
                (void*)&rs_a, (void*)&csr_a,
                (void*)&N_a, (void*)&E_a, (void*)&nb_a, (void*)&db_a, (void*)&pb_a };
            hipError_t err = hipLaunchCooperativeKernel(build_kernel,
                                                        dim3(grid), dim3(256),
                                                        kargs, 0, stream);
            if (err == hipSuccess) built = true;
            else (void)hipGetLastError();            // clear, fall through
        }

        if (!built) {
            prep_kernel<<<5, 256, 0, stream>>>(gcursor, W_self1, W_neigh1,
                                               W_self2, W_neigh2, w1p, w2p);
            if (disjoint) {
                p1_dense1_kernel<<<dblocks + p1blocks, 256, 0, stream>>>(
                    src, dst, gcursor, bucket2, E, nbuckets, dblocks,
                    x, w1p, b1, bufA, t1n, N);
                p2_csr_kernel<<<nbuckets, 256, 0, stream>>>(bucket2, gcursor,
                                                            row_start, csr_src, N, nbuckets);
            } else {
                p1_dense1_kernel<<<p1blocks, 256, 0, stream>>>(
                    src, dst, gcursor, bucket, E, nbuckets, 0,
                    x, w1p, b1, bufA, t1n, N);
                p2_csr_kernel<<<nbuckets, 256, 0, stream>>>(bucket, gcursor,
                                                            row_start, csr_src, N, nbuckets);
                p1_dense1_kernel<<<dblocks, 256, 0, stream>>>(
                    src, dst, gcursor, bucket, E, nbuckets, dblocks,
                    x, w1p, b1, bufA, t1n, N);
            }
        }
        agg64_d2_kernel<<<(N + 15) / 16, 256, 0, stream>>>(
            t1n, bufA, row_start, csr_src, w2p, b2, out, t2n, N, E);
        agg32_kernel<<<(N + 15) / 16, 256, 0, stream>>>(out, t2n,
                                                        row_start, csr_src, N, E);
    } else {
        // fallback: atomic path (~51.6 MB)
        float* deg = (float*)d_ws;
        float* agg = deg + N;
        float* h1  = agg + (size_t)N * NF;
        hipMemsetAsync(deg, 0, (size_t)(N + (size_t)N * NF) * sizeof(float), stream);
        deg_kernel<<<(E + 255) / 256, 256, 0, stream>>>(dst, deg, E);
        int at = E * NF;
        agg_atomic_kernel<<<(at + 255) / 256, 256, 0, stream>>>(x, src, dst, agg, E);
        layer1_fb_kernel<<<(N * NF + 255) / 256, 256, 0, stream>>>(x, agg, deg, W_self1,
                                                                   W_neigh1, b1, h1, N);
        hipMemsetAsync(agg, 0, (size_t)N * NF * sizeof(float), stream);
        agg_atomic_kernel<<<(at + 255) / 256, 256, 0, stream>>>(h1, src, dst, agg, E);
        layer2_fb_kernel<<<(N * 32 + 255) / 256, 256, 0, stream>>>(h1, agg, deg, W_self2,
                                                                   W_neigh2, b2, out, N);
    }
}

// Round 9
// 190.673 us; speedup vs baseline: 3.3945x; 3.3945x over previous
//
#include <hip/hip_runtime.h>
#include <hip/hip_bf16.h>

// GraphSAGE 2-layer forward. N=100000, E=1250000, 64 -> 64 -> 32, fp32.
//
// Round-22: coop fusion abandoned (r19: VGPR-max 128 -> 24% occ; r21: VGPR cap
// -> 280MB scratch spills). This round combines the two proven-good halves:
//   - round-20's build side: NO prep dispatch. gcursor := hipMemsetAsync;
//     dense1 stages Ws1/Wn1 in LDS per block (round-13 body, 36.8KB union);
//     w2p pack rides as 4 extra blocks of dispatch A (consumed only by the
//     agg64 dispatch, 2 dispatches later -> no ordering hazard).
//     (r20 evidence: its build side was ~15us faster than r18's; its loss was
//     entirely the agg-side self-fusion, which is NOT repeated here.)
//   - round-18's agg side, with gather ILP deepened 2->3 per node (6 rows in
//     flight per lane; VGPR ~60, below the 64 occupancy cliff, NO cap).
// Pipeline: memset(gcursor) -> [dense1(LDS) || p1 || w2p-pack] -> p2
//           -> agg64_d2 (3-deep) -> agg32 (3-deep).

#define NF 64
#define BW 256            // bucket width (nodes); rel = dst & 255
#define BSH 8
#define MAXB 512          // max buckets (LDS arrays)
#define CAPMAX 8192       // max edges per bucket region (mean 3197)
#define P1_CHUNK 2048
#define H1S 68            // h1s row stride in floats

typedef __attribute__((ext_vector_type(8))) short short8;
typedef __attribute__((ext_vector_type(8))) unsigned short ushort8v;
typedef __attribute__((ext_vector_type(4))) float floatx4;

__device__ __forceinline__ short bf16hi(float v) {
    __hip_bfloat16 h = __float2bfloat16(v);
    return *(short*)&h;
}
__device__ __forceinline__ float bf2f(short s) {
    __hip_bfloat16 h = *(__hip_bfloat16*)&s;
    return __bfloat162float(h);
}
__device__ __forceinline__ float bits2f(unsigned short u) {
    unsigned int x = ((unsigned int)u) << 16;
    union { unsigned int i; float f; } c; c.i = x; return c.f;
}

// ---------------- dispatch A: dense1 (LDS-staged) || p1 || w2p pack ----------
// Blocks [0, dblocks): dense1 full 128-col (bufA=x@Ws1+b1, t1n=bf16(x@Wn1)),
//   weights staged per block into 36.8KB LDS (round-13 proven body).
// Blocks [dblocks, packBase): p1 bucketing (4KB of the union).
// Blocks [packBase, packBase+4): pack w2p (dense2 weights), consumed only by
//   the agg64 dispatch -> no intra-dispatch ordering requirement.

__global__ __launch_bounds__(256) void d1p1_kernel(
        const int* __restrict__ src, const int* __restrict__ dst,
        int* __restrict__ gcursor, unsigned* __restrict__ bucket,
        int E, int nbuckets, int dblocks, int packBase,
        const float* __restrict__ X,                 // [N][64]
        const float* __restrict__ Wself,             // [64][64] k-major
        const float* __restrict__ Wneigh,            // [64][64] k-major
        const float* __restrict__ bias,              // [64]
        float* __restrict__ outA,                    // [N][64] f32 (xs)
        unsigned short* __restrict__ outB,           // [N][64] bf16 bits (t1n)
        int N,
        const float* __restrict__ Ws2,               // [64][32] k-major
        const float* __restrict__ Wn2,               // [64][32] k-major
        unsigned short* __restrict__ w2p) {          // [8192] dense2 pack hi/lo
    __shared__ __align__(16) int smem_i[9216];       // 36864 B union
    const int tid = threadIdx.x;

    if ((int)blockIdx.x >= packBase) {
        // ---------------- pack w2p ----------------
        const int part = blockIdx.x - packBase;      // 0..3
        for (int i = tid; i < 16 * 64; i += 256) {   // 16 cols per part
            int n = part * 16 + (i >> 6), k = i & 63;
            float v = (n < 32) ? Ws2[k * 32 + n] : Wn2[k * 32 + (n - 32)];
            short hv = bf16hi(v);
            w2p[n * 64 + k] = (unsigned short)hv;
            w2p[4096 + n * 64 + k] = (unsigned short)bf16hi(v - bf2f(hv));
        }
        return;
    }

    if ((int)blockIdx.x >= dblocks) {
        // ---------------- p1: bucket the edge list ----------------
        int* cnt   = smem_i;                         // [MAXB]
        int* cbase = smem_i + MAXB;                  // [MAXB]
        const int bid = blockIdx.x - dblocks;
        const int beg = bid * P1_CHUNK;
        const int end = min(E, beg + P1_CHUNK);
        for (int i = tid; i < nbuckets; i += 256) cnt[i] = 0;
        __syncthreads();
        for (int e = beg + tid; e < end; e += 256)
            atomicAdd(&cnt[dst[e] >> BSH], 1);
        __syncthreads();
        for (int i = tid; i < nbuckets; i += 256) {
            int c = cnt[i];
            cbase[i] = c ? atomicAdd(&gcursor[i], c) : 0;
            cnt[i] = 0;                              // reuse as local cursor
        }
        __syncthreads();
        for (int e = beg + tid; e < end; e += 256) {
            int d = dst[e];
            int r = d >> BSH;
            int p = cbase[r] + atomicAdd(&cnt[r], 1);
            if (p < CAPMAX)                          // clamp: no OOB even if skewed
                bucket[(size_t)r * CAPMAX + p] = ((unsigned)src[e] << BSH) | (unsigned)(d & (BW - 1));
        }
        return;
    }

    // ---------------- dense1: [N][64] @ [64][128] MFMA split-bf16 ----------
    // A: A[m=lane&15][k=(lane>>4)*8+j]; C/D: col=lane&15, row=(lane>>4)*4+reg.
    constexpr int NT = 8, NSELF = 4, NO = 128, HALF = 64;
    unsigned short* wh = (unsigned short*)smem_i;            // [NO*72]
    unsigned short* wl = wh + NO * 72;                       // [NO*72]
    for (int i = tid; i < NO * 64; i += 256) {
        int n = i & (NO - 1), k = i / NO;            // consecutive tid -> coalesced
        float v = (n < HALF) ? Wself[k * HALF + n] : Wneigh[k * HALF + (n - HALF)];
        short hv = bf16hi(v);
        wh[n * 72 + k] = (unsigned short)hv;
        wl[n * 72 + k] = (unsigned short)bf16hi(v - bf2f(hv));
    }

    const int lane = tid & 63;
    const int wid  = tid >> 6;
    const int m = lane & 15, quad = lane >> 4;
    const int rowblk = blockIdx.x * 128 + wid * 32;

    floatx4 acc[2][NT];
    #pragma unroll
    for (int rt = 0; rt < 2; ++rt)
        #pragma unroll
        for (int t = 0; t < NT; ++t) acc[rt][t] = (floatx4)(0.f);

    short8 ah[2][2], al[2][2];   // [rowset][k-half]
    #pragma unroll
    for (int rt = 0; rt < 2; ++rt) {
        int r = rowblk + rt * 16 + m;
        if (r >= N) r = N - 1;                       // clamped load, store guarded
        const float* xp = X + (size_t)r * 64 + quad * 8;
        #pragma unroll
        for (int h = 0; h < 2; ++h) {
            floatx4 f0 = *(const floatx4*)(xp + h * 32);
            floatx4 f1 = *(const floatx4*)(xp + h * 32 + 4);
            short8 hi, lo;
            #pragma unroll
            for (int j = 0; j < 4; ++j) {
                short hv = bf16hi(f0[j]);
                hi[j] = hv; lo[j] = bf16hi(f0[j] - bf2f(hv));
                short hv2 = bf16hi(f1[j]);
                hi[4 + j] = hv2; lo[4 + j] = bf16hi(f1[j] - bf2f(hv2));
            }
            ah[rt][h] = hi; al[rt][h] = lo;
        }
    }
    __syncthreads();                                 // weights staged

    #pragma unroll
    for (int t = 0; t < NT; ++t) {
        int n = t * 16 + m;
        const unsigned short* ph = wh + n * 72 + quad * 8;
        const unsigned short* pl = wl + n * 72 + quad * 8;
        #pragma unroll
        for (int h = 0; h < 2; ++h) {
            short8 bh = *(const short8*)(ph + h * 32);
            short8 bl = *(const short8*)(pl + h * 32);
            #pragma unroll
            for (int rt = 0; rt < 2; ++rt) {
                acc[rt][t] = __builtin_amdgcn_mfma_f32_16x16x32_bf16(ah[rt][h], bh, acc[rt][t], 0, 0, 0);
                acc[rt][t] = __builtin_amdgcn_mfma_f32_16x16x32_bf16(al[rt][h], bh, acc[rt][t], 0, 0, 0);
                acc[rt][t] = __builtin_amdgcn_mfma_f32_16x16x32_bf16(ah[rt][h], bl, acc[rt][t], 0, 0, 0);
            }
        }
    }

    #pragma unroll
    for (int rt = 0; rt < 2; ++rt) {
        #pragma unroll
        for (int t = 0; t < NT; ++t) {
            #pragma unroll
            for (int r4 = 0; r4 < 4; ++r4) {
                int row = rowblk + rt * 16 + quad * 4 + r4;
                if (row < N) {
                    if (t < NSELF) {
                        int col = t * 16 + m;
                        outA[(size_t)row * 64 + col] = acc[rt][t][r4] + bias[col];
                    } else {
                        int col = (t - NSELF) * 16 + m;
                        outB[(size_t)row * 64 + col] = (unsigned short)bf16hi(acc[rt][t][r4]);
                    }
                }
            }
        }
    }
}

// ---------------- p2: per-bucket CSR (exclusive window) ----------------

__global__ __launch_bounds__(256) void p2_csr_kernel(const unsigned* __restrict__ bucket,
                                                     const int* __restrict__ gcursor,
                                                     int* __restrict__ row_start,
                                                     int* __restrict__ csr_src,
                                                     int N, int nbuckets) {
    __shared__ unsigned stage[CAPMAX];   // 32 KB
    __shared__ int cnt[BW];
    __shared__ int excl[BW];
    const int r = blockIdx.x;
    const int tid = threadIdx.x;

    // base = sum_{i<r} min(gcursor[i], CAPMAX)   (excl[] as scratch)
    int partial = 0;
    for (int i = tid; i < r; i += 256) partial += min(gcursor[i], CAPMAX);
    excl[tid] = partial;
    __syncthreads();
    for (int off = 128; off > 0; off >>= 1) {
        if (tid < off) excl[tid] += excl[tid + off];
        __syncthreads();
    }
    const int base = excl[0];
    const int sz = min(gcursor[r], CAPMAX);
    const unsigned* bsrc = bucket + (size_t)r * CAPMAX;
    __syncthreads();

    cnt[tid] = 0;
    __syncthreads();
    for (int i = tid; i < sz; i += 256) {
        unsigned v = bsrc[i];
        stage[i] = v;
        atomicAdd(&cnt[v & (BW - 1)], 1);
    }
    __syncthreads();
    // inclusive scan (Hillis-Steele, 1 elem/thread since BW == blockDim)
    excl[tid] = cnt[tid];
    __syncthreads();
    for (int off = 1; off < BW; off <<= 1) {
        int v0 = (tid >= off) ? excl[tid - off] : 0;
        __syncthreads();
        excl[tid] += v0;
        __syncthreads();
    }
    int node = r * BW + tid;
    if (node < N) row_start[node] = base + excl[tid] - cnt[tid];
    if (r == nbuckets - 1 && tid == 0) row_start[N] = base + sz;
    __syncthreads();
    cnt[tid] = excl[tid] - cnt[tid];             // exclusive cursors
    __syncthreads();
    for (int i = tid; i < sz; i += 256) {
        unsigned v = stage[i];
        int p = atomicAdd(&cnt[v & (BW - 1)], 1);
        csr_src[base + p] = (int)(v >> BSH);     // window owned by this block only
    }
}

// ---------------- fused agg64 + dense2 (3-deep gather) ----------------
// Block = 16 nodes, 4 waves. Half-wave owns TWO nodes; 3-deep per node =
// 6 concurrent row gathers per lane, with next-iteration csr indices
// prefetched. xs + w2p loads issued post-loop.

__global__ __launch_bounds__(256) void agg64_d2_kernel(
        const unsigned short* __restrict__ t1n,      // [N][64] bf16 bits
        const float* __restrict__ xs,                // [N][64] self+bias
        const int* __restrict__ row_start,
        const int* __restrict__ csr_src,
        const unsigned short* __restrict__ w2p,      // packed hi/lo fragments
        const float* __restrict__ b2,                // [32]
        float* __restrict__ outD,                    // [N][32] (d_out)
        unsigned short* __restrict__ t2n,            // [N][32] bf16 bits
        int N, int E) {
    __shared__ float h1s[16][H1S];                   // 4.25 KB, padded stride
    const int tid = threadIdx.x;
    const int lane = tid & 63;
    const int wid  = tid >> 6;
    const int half = lane >> 5;                      // node select within pair
    const int g = (lane >> 3) & 3;                   // 4 groups of 8 per node
    const int c = lane & 7;
    const int nbase = blockIdx.x * 16;

    const int ln0 = wid * 4 + half;                  // this half-wave's 2 nodes
    const int ln1 = ln0 + 2;
    const int n0 = nbase + ln0, n1 = nbase + ln1;
    int beg0 = 0, end0 = 0, beg1 = 0, end1 = 0;
    if (n0 < N) { beg0 = row_start[n0]; end0 = row_start[n0 + 1]; }
    if (n1 < N) { beg1 = row_start[n1]; end1 = row_start[n1 + 1]; }

    float a0[8] = {0.f, 0.f, 0.f, 0.f, 0.f, 0.f, 0.f, 0.f};
    float a1[8] = {0.f, 0.f, 0.f, 0.f, 0.f, 0.f, 0.f, 0.f};
    int j0 = beg0 + g, j1 = beg1 + g;
    const int Em1 = E - 1;
    // prefetched index set for the current iteration (3 per node)
    int i0 = csr_src[min(j0, Em1)];
    int i1 = csr_src[min(j0 + 4, Em1)];
    int i2 = csr_src[min(j0 + 8, Em1)];
    int i3 = csr_src[min(j1, Em1)];
    int i4 = csr_src[min(j1 + 4, Em1)];
    int i5 = csr_src[min(j1 + 8, Em1)];
    while ((j0 < end0) || (j1 < end1)) {
        int s0 = ((unsigned)i0 < (unsigned)N) ? i0 : 0;
        int s1 = ((unsigned)i1 < (unsigned)N) ? i1 : 0;
        int s2 = ((unsigned)i2 < (unsigned)N) ? i2 : 0;
        int s3 = ((unsigned)i3 < (unsigned)N) ? i3 : 0;
        int s4 = ((unsigned)i4 < (unsigned)N) ? i4 : 0;
        int s5 = ((unsigned)i5 < (unsigned)N) ? i5 : 0;
        // 6 concurrent row gathers
        ushort8v u0 = *(const ushort8v*)(t1n + (size_t)s0 * 64 + c * 8);
        ushort8v u1 = *(const ushort8v*)(t1n + (size_t)s1 * 64 + c * 8);
        ushort8v u2 = *(const ushort8v*)(t1n + (size_t)s2 * 64 + c * 8);
        ushort8v u3 = *(const ushort8v*)(t1n + (size_t)s3 * 64 + c * 8);
        ushort8v u4 = *(const ushort8v*)(t1n + (size_t)s4 * 64 + c * 8);
        ushort8v u5 = *(const ushort8v*)(t1n + (size_t)s5 * 64 + c * 8);
        // prefetch next iteration's indices (overlap gather latency)
        i0 = csr_src[min(j0 + 12, Em1)];
        i1 = csr_src[min(j0 + 16, Em1)];
        i2 = csr_src[min(j0 + 20, Em1)];
        i3 = csr_src[min(j1 + 12, Em1)];
        i4 = csr_src[min(j1 + 16, Em1)];
        i5 = csr_src[min(j1 + 20, Em1)];
        const bool c00 = j0 < end0, c01 = j0 + 4 < end0, c02 = j0 + 8 < end0;
        const bool c10 = j1 < end1, c11 = j1 + 4 < end1, c12 = j1 + 8 < end1;
        #pragma unroll
        for (int i = 0; i < 8; ++i) {
            a0[i] += (c00 ? bits2f(u0[i]) : 0.f) + (c01 ? bits2f(u1[i]) : 0.f)
                   + (c02 ? bits2f(u2[i]) : 0.f);
            a1[i] += (c10 ? bits2f(u3[i]) : 0.f) + (c11 ? bits2f(u4[i]) : 0.f)
                   + (c12 ? bits2f(u5[i]) : 0.f);
        }
        j0 += 12; j1 += 12;
    }

    // issue tail loads now; latency hides under reduce + h1s + barrier
    const int m = lane & 15, quad = lane >> 4;
    const int coln = wid * 16 + m;
    const unsigned short* pb = w2p + coln * 64 + quad * 8;
    short8 bhf0 = *(const short8*)(pb);
    short8 bhf1 = *(const short8*)(pb + 32);
    short8 blf0 = *(const short8*)(pb + 4096);
    short8 blf1 = *(const short8*)(pb + 4096 + 32);

    floatx4 x00 = (floatx4)(0.f), x01 = (floatx4)(0.f);
    floatx4 x10 = (floatx4)(0.f), x11 = (floatx4)(0.f);
    if (g == 0) {
        if (n0 < N) {
            const float* p = xs + (size_t)n0 * 64 + c * 8;
            x00 = *(const floatx4*)p; x01 = *(const floatx4*)(p + 4);
        }
        if (n1 < N) {
            const float* p = xs + (size_t)n1 * 64 + c * 8;
            x10 = *(const floatx4*)p; x11 = *(const floatx4*)(p + 4);
        }
    }

    #pragma unroll
    for (int i = 0; i < 8; ++i) {                    // reduce over 4 groups (in-half)
        float v = a0[i];
        v += __shfl_xor(v, 8);
        v += __shfl_xor(v, 16);
        a0[i] = v;
        float w = a1[i];
        w += __shfl_xor(w, 8);
        w += __shfl_xor(w, 16);
        a1[i] = w;
    }
    if (g == 0) {                                    // 8 lanes per half write rows
        floatx4 h0, h1v;
        if (n0 < N) {
            float invd = 1.0f / fmaxf((float)(end0 - beg0), 1.0f);
            #pragma unroll
            for (int i = 0; i < 4; ++i) {
                h0[i]  = fmaxf(x00[i] + a0[i] * invd, 0.f);
                h1v[i] = fmaxf(x01[i] + a0[4 + i] * invd, 0.f);
            }
        } else { h0 = (floatx4)(0.f); h1v = (floatx4)(0.f); }
        *(floatx4*)&h1s[ln0][c * 8]     = h0;
        *(floatx4*)&h1s[ln0][c * 8 + 4] = h1v;
        if (n1 < N) {
            float invd = 1.0f / fmaxf((float)(end1 - beg1), 1.0f);
            #pragma unroll
            for (int i = 0; i < 4; ++i) {
                h0[i]  = fmaxf(x10[i] + a1[i] * invd, 0.f);
                h1v[i] = fmaxf(x11[i] + a1[4 + i] * invd, 0.f);
            }
        } else { h0 = (floatx4)(0.f); h1v = (floatx4)(0.f); }
        *(floatx4*)&h1s[ln1][c * 8]     = h0;
        *(floatx4*)&h1s[ln1][c * 8 + 4] = h1v;
    }
    __syncthreads();                                 // h1 tile ready

    // dense2: wave wid -> output cols wid*16 .. wid*16+15
    short8 ah[2], al[2];                             // A = h1s, split hi/lo
    #pragma unroll
    for (int h = 0; h < 2; ++h) {
        const float* hp = &h1s[m][quad * 8 + h * 32];
        floatx4 f0 = *(const floatx4*)hp;
        floatx4 f1 = *(const floatx4*)(hp + 4);
        short8 hi, lo;
        #pragma unroll
        for (int j = 0; j < 4; ++j) {
            short hv = bf16hi(f0[j]);
            hi[j] = hv; lo[j] = bf16hi(f0[j] - bf2f(hv));
            short hv2 = bf16hi(f1[j]);
            hi[4 + j] = hv2; lo[4 + j] = bf16hi(f1[j] - bf2f(hv2));
        }
        ah[h] = hi; al[h] = lo;
    }
    floatx4 acc2 = (floatx4)(0.f);
    acc2 = __builtin_amdgcn_mfma_f32_16x16x32_bf16(ah[0], bhf0, acc2, 0, 0, 0);
    acc2 = __builtin_amdgcn_mfma_f32_16x16x32_bf16(al[0], bhf0, acc2, 0, 0, 0);
    acc2 = __builtin_amdgcn_mfma_f32_16x16x32_bf16(ah[0], blf0, acc2, 0, 0, 0);
    acc2 = __builtin_amdgcn_mfma_f32_16x16x32_bf16(ah[1], bhf1, acc2, 0, 0, 0);
    acc2 = __builtin_amdgcn_mfma_f32_16x16x32_bf16(al[1], bhf1, acc2, 0, 0, 0);
    acc2 = __builtin_amdgcn_mfma_f32_16x16x32_bf16(ah[1], blf1, acc2, 0, 0, 0);
    #pragma unroll
    for (int r4 = 0; r4 < 4; ++r4) {
        int node = nbase + quad * 4 + r4;
        if (node < N) {
            if (coln < 32) outD[(size_t)node * 32 + coln] = acc2[r4] + b2[coln];
            else t2n[(size_t)node * 32 + (coln - 32)] = (unsigned short)bf16hi(acc2[r4]);
        }
    }
}

// ---------------- agg32: d_out += mean t2n[src], in place (3-deep) ----------
// 16-lane group per node (4 edge-groups x 3-deep), 4 nodes/wave, 6250 blocks.

__global__ __launch_bounds__(256) void agg32_kernel(float* io,  // [N][32] (d_out)
                                                    const unsigned short* __restrict__ t2n,
                                                    const int* __restrict__ row_start,
                                                    const int* __restrict__ csr_src,
                                                    int N, int E) {
    const int tid = threadIdx.x;
    const int lane = tid & 63;
    const int wid = tid >> 6;
    const int slot = lane >> 4;                      // 4 nodes per wave
    const int g = (lane >> 2) & 3;                   // 4 edge-groups per node
    const int c = lane & 3;                          // 16B chunk of 64B row
    const int n = blockIdx.x * 16 + wid * 4 + slot;

    int beg = 0, end = 0;
    if (n < N) { beg = row_start[n]; end = row_start[n + 1]; }

    // hoist in-place read: overlaps the gather chain instead of trailing it
    floatx4 s0v = (floatx4)(0.f), s1v = (floatx4)(0.f);
    size_t o = (size_t)n * 32 + c * 8;
    if (n < N && g == 0) {
        s0v = *(const floatx4*)(io + o);
        s1v = *(const floatx4*)(io + o + 4);
    }

    float acc[8] = {0.f, 0.f, 0.f, 0.f, 0.f, 0.f, 0.f, 0.f};
    const int Em1 = E - 1;
    for (int j = beg + g; j < end; j += 12) {
        int s0 = csr_src[j];                         // j < end <= E guaranteed
        int s1 = csr_src[min(j + 4, Em1)];
        int s2 = csr_src[min(j + 8, Em1)];
        s0 = ((unsigned)s0 < (unsigned)N) ? s0 : 0;
        s1 = ((unsigned)s1 < (unsigned)N) ? s1 : 0;
        s2 = ((unsigned)s2 < (unsigned)N) ? s2 : 0;
        ushort8v u0 = *(const ushort8v*)(t2n + (size_t)s0 * 32 + c * 8);
        ushort8v u1 = *(const ushort8v*)(t2n + (size_t)s1 * 32 + c * 8);
        ushort8v u2 = *(const ushort8v*)(t2n + (size_t)s2 * 32 + c * 8);
        const bool c1 = j + 4 < end, c2 = j + 8 < end;
        #pragma unroll
        for (int i = 0; i < 8; ++i)
            acc[i] += bits2f(u0[i]) + (c1 ? bits2f(u1[i]) : 0.f)
                    + (c2 ? bits2f(u2[i]) : 0.f);
    }
    #pragma unroll
    for (int i = 0; i < 8; ++i) {                    // reduce over 4 groups (16-lane)
        float v = acc[i];
        v += __shfl_xor(v, 4);
        v += __shfl_xor(v, 8);
        acc[i] = v;
    }
    if (n < N && g == 0) {
        float inv = 1.0f / fmaxf((float)(end - beg), 1.0f);
        floatx4 r0, r1;
        #pragma unroll
        for (int i = 0; i < 4; ++i) {
            r0[i] = s0v[i] + acc[i] * inv;
            r1[i] = s1v[i] + acc[4 + i] * inv;
        }
        *(floatx4*)(io + o) = r0;
        *(floatx4*)(io + o + 4) = r1;
    }
}

// ---------------- fallback (round-2 atomic path) ----------------

__global__ __launch_bounds__(256) void deg_kernel(const int* __restrict__ dst,
                                                  float* __restrict__ deg, int E) {
    int e = blockIdx.x * blockDim.x + threadIdx.x;
    if (e < E) atomicAdd(&deg[dst[e]], 1.0f);
}

__global__ __launch_bounds__(256) void agg_atomic_kernel(const float* __restrict__ feats,
                                                         const int* __restrict__ src,
                                                         const int* __restrict__ dst,
                                                         float* __restrict__ agg, int E) {
    int tid = blockIdx.x * blockDim.x + threadIdx.x;
    if (tid >= E * NF) return;
    int e = tid >> 6, f = tid & 63;
    atomicAdd(&agg[(size_t)dst[e] * NF + f], feats[(size_t)src[e] * NF + f]);
}

__global__ __launch_bounds__(256) void layer1_fb_kernel(const float* __restrict__ x,
                                                        const float* __restrict__ agg,
                                                        const float* __restrict__ deg,
                                                        const float* __restrict__ Wself,
                                                        const float* __restrict__ Wneigh,
                                                        const float* __restrict__ b,
                                                        float* __restrict__ h1, int N) {
    int tid = blockIdx.x * blockDim.x + threadIdx.x;
    if (tid >= N * NF) return;
    int n = tid >> 6, c = tid & 63;
    float inv = 1.0f / fmaxf(deg[n], 1.0f);
    const float* xrow = x + (size_t)n * NF;
    const float* arow = agg + (size_t)n * NF;
    float acc = b[c];
    #pragma unroll
    for (int k = 0; k < NF; ++k) {
        acc += xrow[k] * Wself[k * NF + c];
        acc += (arow[k] * inv) * Wneigh[k * NF + c];
    }
    h1[tid] = fmaxf(acc, 0.f);
}

__global__ __launch_bounds__(256) void layer2_fb_kernel(const float* __restrict__ h1,
                                                        const float* __restrict__ agg,
                                                        const float* __restrict__ deg,
                                                        const float* __restrict__ Wself,
                                                        const float* __restrict__ Wneigh,
                                                        const float* __restrict__ b,
                                                        float* __restrict__ out, int N) {
    int tid = blockIdx.x * blockDim.x + threadIdx.x;
    if (tid >= N * 32) return;
    int n = tid >> 5, c = tid & 31;
    float inv = 1.0f / fmaxf(deg[n], 1.0f);
    const float* hrow = h1 + (size_t)n * NF;
    const float* arow = agg + (size_t)n * NF;
    float acc = b[c];
    #pragma unroll
    for (int k = 0; k < NF; ++k) {
        acc += hrow[k] * Wself[k * 32 + c];
        acc += (arow[k] * inv) * Wneigh[k * 32 + c];
    }
    out[tid] = acc;
}

// ---------------- launch ----------------

extern "C" void kernel_launch(void* const* d_in, const int* in_sizes, int n_in,
                              void* d_out, int out_size, void* d_ws, size_t ws_size,
                              hipStream_t stream) {
    const float* x        = (const float*)d_in[0];
    const int*   src      = (const int*)d_in[1];
    const int*   dst      = (const int*)d_in[2];
    const float* W_self1  = (const float*)d_in[3];
    const float* W_neigh1 = (const float*)d_in[4];
    const float* b1       = (const float*)d_in[5];
    const float* W_self2  = (const float*)d_in[6];
    const float* W_neigh2 = (const float*)d_in[7];
    const float* b2       = (const float*)d_in[8];
    float* out = (float*)d_out;

    const int N = in_sizes[0] / NF;          // 100000
    const int E = in_sizes[1];               // 1250000
    const int nbuckets = (N + BW - 1) / BW;  // 391

    // ws layout; gather tables 128B-aligned (round-10 proven)
    const size_t rsPad = ((size_t)N + 8) & ~7ull;
    int* gcursor   = (int*)d_ws;                      // [MAXB]
    unsigned short* w2p = (unsigned short*)(gcursor + MAXB);  // [8192] (16 KB)
    int* row_start = (int*)(w2p + 8192);              // [N+1] padded
    int* csr_src   = row_start + rsPad;               // [E]
    uintptr_t pa = (uintptr_t)(csr_src + (((size_t)E + 7) & ~7ull));
    pa = (pa + 127) & ~(uintptr_t)127;                // 128B align
    float* bufA = (float*)pa;                         // [N][64] f32 (xs)
    unsigned* bucket = (unsigned*)bufA;               // alias (serialized fallback only)
    unsigned short* t1n = (unsigned short*)(bufA + (size_t)N * NF);  // [N][64] bf16
    unsigned short* t2n = t1n + (size_t)N * NF;                      // [N][32] bf16
    size_t need = (size_t)((char*)(t2n + (size_t)N * 32) - (char*)d_ws);  // ~50.3 MB

    bool fast = ws_size >= need
             && E > 0 && N > 0
             && nbuckets <= MAXB
             && (size_t)nbuckets * CAPMAX <= (size_t)N * NF
             && (size_t)E * 2 / (size_t)nbuckets <= CAPMAX
             && N < (1 << 24)
             && out_size >= N * 32;

    if (fast) {
        const int dblocks  = (N + 127) / 128;                    // 782
        const int p1blocks = (E + P1_CHUNK - 1) / P1_CHUNK;      // 611
        unsigned* bucket2 = (unsigned*)(t2n + (((size_t)N * 32 + 63) & ~63ull));
        size_t need2 = (size_t)((char*)(bucket2 + (size_t)nbuckets * CAPMAX) - (char*)d_ws);
        hipMemsetAsync(gcursor, 0, MAXB * sizeof(int), stream);
        if (ws_size >= need2) {
            // fused: dense1 || p1 || pack in one dispatch (disjoint bucket2)
            d1p1_kernel<<<dblocks + p1blocks + 4, 256, 0, stream>>>(
                src, dst, gcursor, bucket2, E, nbuckets, dblocks,
                dblocks + p1blocks,
                x, W_self1, W_neigh1, b1, bufA, t1n, N,
                W_self2, W_neigh2, w2p);
            p2_csr_kernel<<<nbuckets, 256, 0, stream>>>(bucket2, gcursor,
                                                        row_start, csr_src, N, nbuckets);
        } else {
            // tight ws: p1+pack first (bucket aliases bufA), then p2, then dense1
            d1p1_kernel<<<p1blocks + 4, 256, 0, stream>>>(
                src, dst, gcursor, bucket, E, nbuckets, 0, p1blocks,
                x, W_self1, W_neigh1, b1, bufA, t1n, N,
                W_self2, W_neigh2, w2p);
            p2_csr_kernel<<<nbuckets, 256, 0, stream>>>(bucket, gcursor,
                                                        row_start, csr_src, N, nbuckets);
            d1p1_kernel<<<dblocks, 256, 0, stream>>>(
                src, dst, gcursor, bucket, E, nbuckets, dblocks,
                dblocks + p1blocks,                  // unreachable: no pack blocks
                x, W_self1, W_neigh1, b1, bufA, t1n, N,
                W_self2, W_neigh2, w2p);
        }
        agg64_d2_kernel<<<(N + 15) / 16, 256, 0, stream>>>(
            t1n, bufA, row_start, csr_src, w2p, b2, out, t2n, N, E);
        agg32_kernel<<<(N + 15) / 16, 256, 0, stream>>>(out, t2n,
                                                        row_start, csr_src, N, E);
    } else {
        // fallback: atomic path (~51.6 MB)
        float* deg = (float*)d_ws;
        float* agg = deg + N;
        float* h1  = agg + (size_t)N * NF;
        hipMemsetAsync(deg, 0, (size_t)(N + (size_t)N * NF) * sizeof(float), stream);
        deg_kernel<<<(E + 255) / 256, 256, 0, stream>>>(dst, deg, E);
        int at = E * NF;
        agg_atomic_kernel<<<(at + 255) / 256, 256, 0, stream>>>(x, src, dst, agg, E);
        layer1_fb_kernel<<<(N * NF + 255) / 256, 256, 0, stream>>>(x, agg, deg, W_self1,
                                                                   W_neigh1, b1, h1, N);
        hipMemsetAsync(agg, 0, (size_t)N * NF * sizeof(float), stream);
        agg_atomic_kernel<<<(at + 255) / 256, 256, 0, stream>>>(h1, src, dst, agg, E);
        layer2_fb_kernel<<<(N * 32 + 255) / 256, 256, 0, stream>>>(h1, agg, deg, W_self2,
                                                                   W_neigh2, b2, out, N);
    }
}